// Round 3
// baseline (515.500 us; speedup 1.0000x reference)
//
#include <hip/hip_runtime.h>
#include <hip/hip_bf16.h>

#define T_TOK 8192
#define D_IN  4096
#define D_OUT 4096
#define SCALE 2.0f

typedef _Float16 h2 __attribute__((ext_vector_type(2)));
typedef _Float16 h8 __attribute__((ext_vector_type(8)));

__device__ __forceinline__ h2 pkrtz(float a, float b) {
    auto r = __builtin_amdgcn_cvt_pkrtz(a, b);   // __fp16 ext_vector(2)
    h2 o; __builtin_memcpy(&o, &r, 4); return o;
}

#if __has_builtin(__builtin_amdgcn_fdot2)
__device__ __forceinline__ float fdot2(h2 a, h2 b, float c) {
    return __builtin_amdgcn_fdot2(a, b, c, false);
}
#else
__device__ __forceinline__ float fdot2(h2 a, h2 b, float c) {
    return c + (float)a.x * (float)b.x + (float)a.y * (float)b.y;
}
#endif

// ------------- Wa f32 -> f16, lane-swizzled so k1 lanes load contiguous 16B --
// WaH[er*4096 + lane*64 + q], q = kc*32 + j*4 + c  <->  k = kc*2048 + j*256 + lane*4 + c
__global__ void conv_wa(const float* __restrict__ Wa, _Float16* __restrict__ WaH) {
    int gid = blockIdx.x * 256 + threadIdx.x;   // 65536 threads, 4 elems each
    int idx = gid * 4;                          // q-aligned to 4 (single j, c=0..3)
    int er   = idx >> 12;
    int rem  = idx & 4095;
    int lane = rem >> 6;
    int q    = rem & 63;
    int kc = q >> 5, j = (q >> 2) & 7;
    int k  = kc * 2048 + j * 256 + lane * 4;
    float4 v = *(const float4*)(Wa + (size_t)er * 4096 + k);
    *(h2*)(WaH + idx)     = pkrtz(v.x, v.y);
    *(h2*)(WaH + idx + 2) = pkrtz(v.z, v.w);
}

// ------------- Kernel 1: routing + mid. ONE WAVE PER TOKEN, f16 dot2 --------
__global__ __launch_bounds__(256)
void k1_mid(const float* __restrict__ x, const float* __restrict__ la,
            const float* __restrict__ lb, const _Float16* __restrict__ WaH,
            float* __restrict__ mvec, int* __restrict__ fidx) {
    const int tx   = threadIdx.x;
    const int lane = tx & 63;
    const int t    = blockIdx.x * 4 + (tx >> 6);

    // --- routing A (all lanes redundantly; broadcast loads) ---
    float l[8];
#pragma unroll
    for (int i = 0; i < 8; ++i) l[i] = la[t * 8 + i];
    int ea0 = 0; float b0 = l[0];
#pragma unroll
    for (int i = 1; i < 8; ++i) if (l[i] > b0) { b0 = l[i]; ea0 = i; }
    int ea1 = -1; float b1 = -1e30f;
#pragma unroll
    for (int i = 0; i < 8; ++i) if (i != ea0 && l[i] > b1) { b1 = l[i]; ea1 = i; }
    float wa1 = __expf(b1 - b0); float sa = 1.0f + wa1;
    float wa0 = 1.0f / sa; wa1 = wa1 / sa;

    // --- routing B ---
#pragma unroll
    for (int i = 0; i < 8; ++i) l[i] = lb[t * 8 + i];
    int f0 = 0; float c0 = l[0];
#pragma unroll
    for (int i = 1; i < 8; ++i) if (l[i] > c0) { c0 = l[i]; f0 = i; }
    int f1 = -1; float c1 = -1e30f;
#pragma unroll
    for (int i = 0; i < 8; ++i) if (i != f0 && l[i] > c1) { c1 = l[i]; f1 = i; }
    float wb1 = __expf(c1 - c0); float sb = 1.0f + wb1;
    float wb0 = 1.0f / sb; wb1 = wb1 / sb;

    const int e0s = __builtin_amdgcn_readfirstlane(ea0);
    const int e1s = __builtin_amdgcn_readfirstlane(ea1);

    float vals[16];
#pragma unroll
    for (int v = 0; v < 16; ++v) vals[v] = 0.f;

    const float4* xp = (const float4*)(x + (size_t)t * D_IN);
#pragma unroll
    for (int kc = 0; kc < 2; ++kc) {
        // x chunk: 32 floats/lane, coalesced float4 loads, convert to 16 half2
        h2 xh[16];
#pragma unroll
        for (int j = 0; j < 8; ++j) {
            float4 v = xp[kc * 512 + j * 64 + lane];
            xh[2 * j]     = pkrtz(v.x, v.y);
            xh[2 * j + 1] = pkrtz(v.z, v.w);
        }
#pragma unroll
        for (int slot = 0; slot < 2; ++slot) {
            const int e = slot ? e1s : e0s;
            const h8* wp = (const h8*)(WaH + (size_t)e * 8 * 4096 + lane * 64 + kc * 32);
#pragma unroll
            for (int r = 0; r < 8; ++r) {
                float s = vals[slot * 8 + r];
#pragma unroll
                for (int u = 0; u < 4; ++u) {
                    h8 w = wp[r * 512 + u];   // 8 f16 contiguous (16B)
                    h2 w0 = __builtin_shufflevector(w, w, 0, 1);
                    h2 w1 = __builtin_shufflevector(w, w, 2, 3);
                    h2 w2 = __builtin_shufflevector(w, w, 4, 5);
                    h2 w3 = __builtin_shufflevector(w, w, 6, 7);
                    s = fdot2(xh[4 * u],     w0, s);
                    s = fdot2(xh[4 * u + 1], w1, s);
                    s = fdot2(xh[4 * u + 2], w2, s);
                    s = fdot2(xh[4 * u + 3], w3, s);
                }
                vals[slot * 8 + r] = s;
            }
        }
    }

    // --- butterfly reduce each of 16 values across the wave ---
#pragma unroll
    for (int v = 0; v < 16; ++v) {
        float s = vals[v];
#pragma unroll
        for (int m = 32; m; m >>= 1) s += __shfl_xor(s, m, 64);
        vals[v] = s;
    }

    if (lane == 0) {
        float m[8];
#pragma unroll
        for (int r = 0; r < 8; ++r) m[r] = wa0 * vals[r] + wa1 * vals[8 + r];
        float4* op = (float4*)(mvec + t * 16);
        op[0] = make_float4(SCALE * wb0 * m[0], SCALE * wb0 * m[1], SCALE * wb0 * m[2], SCALE * wb0 * m[3]);
        op[1] = make_float4(SCALE * wb0 * m[4], SCALE * wb0 * m[5], SCALE * wb0 * m[6], SCALE * wb0 * m[7]);
        op[2] = make_float4(SCALE * wb1 * m[0], SCALE * wb1 * m[1], SCALE * wb1 * m[2], SCALE * wb1 * m[3]);
        op[3] = make_float4(SCALE * wb1 * m[4], SCALE * wb1 * m[5], SCALE * wb1 * m[6], SCALE * wb1 * m[7]);
        fidx[2 * t] = f0; fidx[2 * t + 1] = f1;
    }
}

// ------------- Kernel 2: out, LDS-staged m/idx per 256-token chunk ----------
__device__ __forceinline__ float dot8(const float4& lo, const float4& hi,
                                      const float4& ma, const float4& mb) {
    return lo.x * ma.x + lo.y * ma.y + lo.z * ma.z + lo.w * ma.w
         + hi.x * mb.x + hi.y * mb.y + hi.z * mb.z + hi.w * mb.w;
}

__global__ __launch_bounds__(256)
void k2_out(const float* __restrict__ Wb, const float* __restrict__ mvec,
            const int* __restrict__ fidx, float* __restrict__ out) {
    __shared__ float sm[256 * 16];
    __shared__ int   sidx[512];
    const int tx = threadIdx.x;
    const int o  = blockIdx.x * 256 + tx;
    const int tb = blockIdx.y * 256;

    // cooperative staging (coalesced)
    const float4* gmp = (const float4*)(mvec + (size_t)tb * 16);
    float4* smp = (float4*)sm;
#pragma unroll
    for (int i = 0; i < 4; ++i) smp[i * 256 + tx] = gmp[i * 256 + tx];
    if (tx < 128) ((int4*)sidx)[tx] = ((const int4*)(fidx + tb * 2))[tx];

    // all 8 experts' Wb row for this output column: 64 floats in regs
    float4 Wlo[8], Whi[8];
#pragma unroll
    for (int e = 0; e < 8; ++e) {
        const float4* wp = (const float4*)(Wb + ((size_t)e * D_OUT + o) * 8);
        Wlo[e] = wp[0]; Whi[e] = wp[1];
    }
    __syncthreads();

#pragma unroll 4
    for (int t = 0; t < 256; ++t) {
        int e0 = __builtin_amdgcn_readfirstlane(sidx[2 * t]);
        int e1 = __builtin_amdgcn_readfirstlane(sidx[2 * t + 1]);
        const float4* mp = (const float4*)(sm + t * 16);
        float4 m0a = mp[0], m0b = mp[1], m1a = mp[2], m1b = mp[3];

        float acc;
        switch (e0) {
            case 0: acc = dot8(Wlo[0], Whi[0], m0a, m0b); break;
            case 1: acc = dot8(Wlo[1], Whi[1], m0a, m0b); break;
            case 2: acc = dot8(Wlo[2], Whi[2], m0a, m0b); break;
            case 3: acc = dot8(Wlo[3], Whi[3], m0a, m0b); break;
            case 4: acc = dot8(Wlo[4], Whi[4], m0a, m0b); break;
            case 5: acc = dot8(Wlo[5], Whi[5], m0a, m0b); break;
            case 6: acc = dot8(Wlo[6], Whi[6], m0a, m0b); break;
            default: acc = dot8(Wlo[7], Whi[7], m0a, m0b); break;
        }
        switch (e1) {
            case 0: acc += dot8(Wlo[0], Whi[0], m1a, m1b); break;
            case 1: acc += dot8(Wlo[1], Whi[1], m1a, m1b); break;
            case 2: acc += dot8(Wlo[2], Whi[2], m1a, m1b); break;
            case 3: acc += dot8(Wlo[3], Whi[3], m1a, m1b); break;
            case 4: acc += dot8(Wlo[4], Whi[4], m1a, m1b); break;
            case 5: acc += dot8(Wlo[5], Whi[5], m1a, m1b); break;
            case 6: acc += dot8(Wlo[6], Whi[6], m1a, m1b); break;
            default: acc += dot8(Wlo[7], Whi[7], m1a, m1b); break;
        }
        out[(size_t)(tb + t) * D_OUT + o] = acc;
    }
}

// ---------------- aux losses: deterministic two-stage f64 reduction ----------
__global__ void aux_partial(const float* __restrict__ la, const float* __restrict__ lb,
                            double* __restrict__ part) {
    const int tx = threadIdx.x;
    const int t  = blockIdx.x * 256 + tx;
    double loc[16];
    {
        float l[8];
#pragma unroll
        for (int i = 0; i < 8; ++i) l[i] = la[t * 8 + i];
        float m = l[0];
#pragma unroll
        for (int i = 1; i < 8; ++i) m = fmaxf(m, l[i]);
        float s = 0.f; float e[8];
#pragma unroll
        for (int i = 0; i < 8; ++i) { e[i] = __expf(l[i] - m); s += e[i]; }
#pragma unroll
        for (int i = 0; i < 8; ++i) loc[i] = (double)(e[i] / s);
    }
    {
        float l[8];
#pragma unroll
        for (int i = 0; i < 8; ++i) l[i] = lb[t * 8 + i];
        float m = l[0];
#pragma unroll
        for (int i = 1; i < 8; ++i) m = fmaxf(m, l[i]);
        float s = 0.f; float e[8];
#pragma unroll
        for (int i = 0; i < 8; ++i) { e[i] = __expf(l[i] - m); s += e[i]; }
#pragma unroll
        for (int i = 0; i < 8; ++i) loc[8 + i] = (double)(e[i] / s);
    }
    __shared__ double red[4][16];
    const int lane = tx & 63, wid = tx >> 6;
#pragma unroll
    for (int v = 0; v < 16; ++v) {
        double s = loc[v];
#pragma unroll
        for (int off = 32; off > 0; off >>= 1) s += __shfl_down(s, off, 64);
        if (lane == 0) red[wid][v] = s;
    }
    __syncthreads();
    if (tx < 16)
        part[blockIdx.x * 16 + tx] = red[0][tx] + red[1][tx] + red[2][tx] + red[3][tx];
}

__global__ void aux_final(const double* __restrict__ part, float* __restrict__ out_aux) {
    const int tx = threadIdx.x;
    __shared__ double sl[16];
    if (tx < 16) {
        double s = 0.0;
#pragma unroll
        for (int b = 0; b < 32; ++b) s += part[b * 16 + tx];
        sl[tx] = s;
    }
    __syncthreads();
    if (tx == 0) {
        double pa[8], pb[8], ma = 0.0, mb = 0.0;
        for (int e = 0; e < 8; ++e) { pa[e] = sl[e] / 8192.0;     ma += pa[e] / 8.0; }
        for (int e = 0; e < 8; ++e) { pb[e] = sl[8 + e] / 8192.0; mb += pb[e] / 8.0; }
        double va = 0.0, vb = 0.0;
        for (int e = 0; e < 8; ++e) { double d = pa[e] - ma; va += d * d; }
        for (int e = 0; e < 8; ++e) { double d = pb[e] - mb; vb += d * d; }
        va /= 7.0; vb /= 7.0;
        out_aux[0] = (float)(8.0 * va);
        out_aux[1] = (float)(8.0 * vb);
    }
}

extern "C" void kernel_launch(void* const* d_in, const int* in_sizes, int n_in,
                              void* d_out, int out_size, void* d_ws, size_t ws_size,
                              hipStream_t stream) {
    const float* x  = (const float*)d_in[0];
    const float* la = (const float*)d_in[1];
    const float* lb = (const float*)d_in[2];
    const float* Wa = (const float*)d_in[3];
    const float* Wb = (const float*)d_in[4];
    float* out = (float*)d_out;

    char* ws = (char*)d_ws;
    _Float16* WaH = (_Float16*)ws;                               // 512 KB
    float* mvec = (float*)(ws + 524288);                         // 512 KB
    int*   fidx = (int*)(ws + 1048576);                          // 64 KB
    double* part = (double*)(ws + 1114112);                      // 4 KB

    conv_wa<<<256, 256, 0, stream>>>(Wa, WaH);
    aux_partial<<<32, 256, 0, stream>>>(la, lb, part);
    k1_mid<<<2048, 256, 0, stream>>>(x, la, lb, WaH, mvec, fidx);
    k2_out<<<dim3(16, 32), 256, 0, stream>>>(Wb, mvec, fidx, out);
    aux_final<<<1, 64, 0, stream>>>(part, out + (size_t)T_TOK * D_OUT);
}

// Round 5
// 274.482 us; speedup vs baseline: 1.8781x; 1.8781x over previous
//
#include <hip/hip_runtime.h>
#include <hip/hip_bf16.h>

#define T_TOK 8192
#define D_IN  4096
#define D_OUT 4096
#define SCALE 2.0f

typedef _Float16 h2 __attribute__((ext_vector_type(2)));
typedef _Float16 h4 __attribute__((ext_vector_type(4)));
typedef _Float16 h8 __attribute__((ext_vector_type(8)));
typedef float    f4v __attribute__((ext_vector_type(4)));

__device__ __forceinline__ h2 pkrtz(float a, float b) {
    auto r = __builtin_amdgcn_cvt_pkrtz(a, b);
    h2 o; __builtin_memcpy(&o, &r, 4); return o;
}

// MFMA 16x16x32 f16 layouts (verified m89/m91/m120):
//   A-frag: lane holds A[m=lane&15][k=(lane>>4)*8+j], j=0..7 (one 16B h8)
//   B-frag: lane holds B[k=(lane>>4)*8+j][n=lane&15]
//   C/D:    row=(lane>>4)*4+reg, col=lane&15
// Unified fragment-chunk layout for a KxN panel: off = ((k>>3)*N + n)*8 + (k&7)

// ---- conv Wa [er][k] f32 -> WaB f16 fragment order (N=64) -------------------
// 65536 float4s -> 256 blocks x 256 threads
__global__ void cwa(const float* __restrict__ Wa, _Float16* __restrict__ WaB) {
    int gid = blockIdx.x * 256 + threadIdx.x;    // 0..65535
    int er  = gid >> 10;                         // 0..63
    int k0  = (gid & 1023) * 4;
    float4 v = ((const float4*)Wa)[gid];
    int hoff = ((k0 >> 3) * 64 + er) * 8 + (k0 & 7);
    h2 p0 = pkrtz(v.x, v.y), p1 = pkrtz(v.z, v.w);
    h4 o = { p0.x, p0.y, p1.x, p1.y };
    *(h4*)(WaB + hoff) = o;
}

// ---- conv Wb [e][o][r] f32 -> WbB f16 fragment order per 256-col tile -------
// off = nt*16384 + ((er>>3)*256 + (o&255))*8 + (er&7), er = e*8+r (K dim)
__global__ void cwb(const float* __restrict__ Wb, _Float16* __restrict__ WbB) {
    int gid = blockIdx.x * 256 + threadIdx.x;    // 0..262143
    int o = gid & 4095, er = gid >> 12;
    int e = er >> 3, r = er & 7;
    float v = Wb[((size_t)e * 4096 + o) * 8 + r];
    int nt = o >> 8, nl = o & 255;
    WbB[(size_t)nt * 16384 + ((er >> 3) * 256 + nl) * 8 + (er & 7)] = (_Float16)v;
}

// ---- GEMM1: part[c][t][er] = X[t][kc] . WaT[kc][er], M-tile 32 --------------
__global__ __launch_bounds__(256)
void g1(const float* __restrict__ x, const _Float16* __restrict__ WaB,
        float* __restrict__ part, int kch) {
    __shared__ _Float16 lA[16 * 33 * 8];   // 8448 B, pad 32->33 rows
    __shared__ _Float16 lB[16 * 64 * 8];   // 16 KB
    const int tx = threadIdx.x, l = tx & 63, w = tx >> 6;
    const int m0 = blockIdx.x * 32;
    const int kb = blockIdx.y * kch;
    const int mf = w >> 1, nh = w & 1;

    f4v acc[2];
    acc[0] = (f4v){0.f, 0.f, 0.f, 0.f};
    acc[1] = (f4v){0.f, 0.f, 0.f, 0.f};

    const int iters = kch >> 7;
    for (int it = 0; it < iters; ++it) {
        __syncthreads();
        // stage A: 32 rows x 128 k, coalesced float4 reads, b64 LDS writes
        const float4* xg = (const float4*)(x + (size_t)m0 * D_IN + kb + it * 128);
#pragma unroll
        for (int i = 0; i < 4; ++i) {
            int f = i * 256 + tx;            // 0..1023
            int row = f >> 5, c4 = f & 31;
            float4 v = xg[row * 1024 + c4];
            int k = c4 * 4;
            h2 p0 = pkrtz(v.x, v.y), p1 = pkrtz(v.z, v.w);
            h4 o = { p0.x, p0.y, p1.x, p1.y };
            *(h4*)(lA + ((k >> 3) * 33 + row) * 8 + (k & 7)) = o;
        }
        // stage B: 16 KB contiguous copy from WaB window
        const uint4* bg = (const uint4*)(WaB + (((size_t)kb + it * 128) >> 3) * 512);
        uint4* lb4 = (uint4*)lB;
#pragma unroll
        for (int i = 0; i < 4; ++i) lb4[i * 256 + tx] = bg[i * 256 + tx];
        __syncthreads();

#pragma unroll
        for (int ks = 0; ks < 4; ++ks) {
            h8 a = *(const h8*)(lA + ((ks * 4 + (l >> 4)) * 33 + mf * 16 + (l & 15)) * 8);
#pragma unroll
            for (int n2 = 0; n2 < 2; ++n2) {
                int nf = nh * 2 + n2;
                h8 b = *(const h8*)(lB + ((ks * 4 + (l >> 4)) * 64 + nf * 16 + (l & 15)) * 8);
                acc[n2] = __builtin_amdgcn_mfma_f32_16x16x32_f16(a, b, acc[n2], 0, 0, 0);
            }
        }
    }
    float* pp = part + (size_t)blockIdx.y * T_TOK * 64;
#pragma unroll
    for (int n2 = 0; n2 < 2; ++n2)
#pragma unroll
        for (int r = 0; r < 4; ++r)
            pp[(size_t)(m0 + mf * 16 + (l >> 4) * 4 + r) * 64
               + nh * 32 + n2 * 16 + (l & 15)] = acc[n2][r];
}

// ---- combine: K-split sum + routing A/B weighting -> Mbig f16 ---------------
// Mbig = GEMM2 A panels: (t>>6)*4096 + ((er>>3)*64 + (t&63))*8 + (er&7)
__global__ __launch_bounds__(256)
void comb(const float* __restrict__ part, const float* __restrict__ la,
          const float* __restrict__ lb, _Float16* __restrict__ Mb, int ksplit) {
    const int tx = threadIdx.x, l = tx & 63;
    const int t = blockIdx.x * 4 + (tx >> 6);

    float lg[8];
#pragma unroll
    for (int i = 0; i < 8; ++i) lg[i] = la[t * 8 + i];
    int ea0 = 0; float b0 = lg[0];
#pragma unroll
    for (int i = 1; i < 8; ++i) if (lg[i] > b0) { b0 = lg[i]; ea0 = i; }
    int ea1 = -1; float b1 = -1e30f;
#pragma unroll
    for (int i = 0; i < 8; ++i) if (i != ea0 && lg[i] > b1) { b1 = lg[i]; ea1 = i; }
    float wa1 = __expf(b1 - b0); float sa = 1.0f + wa1;
    float wa0 = 1.0f / sa; wa1 = wa1 / sa;

#pragma unroll
    for (int i = 0; i < 8; ++i) lg[i] = lb[t * 8 + i];
    int f0 = 0; float c0 = lg[0];
#pragma unroll
    for (int i = 1; i < 8; ++i) if (lg[i] > c0) { c0 = lg[i]; f0 = i; }
    int f1 = -1; float c1 = -1e30f;
#pragma unroll
    for (int i = 0; i < 8; ++i) if (i != f0 && lg[i] > c1) { c1 = lg[i]; f1 = i; }
    float wb1 = __expf(c1 - c0); float sb = 1.0f + wb1;
    float wb0 = 1.0f / sb; wb1 = wb1 / sb;

    float s = 0.f;
    for (int c = 0; c < ksplit; ++c) s += part[((size_t)c * T_TOK + t) * 64 + l];

    float a0 = __shfl(s, ea0 * 8 + (l & 7), 64);
    float a1 = __shfl(s, ea1 * 8 + (l & 7), 64);
    float mid = wa0 * a0 + wa1 * a1;
    int e = l >> 3;
    float coef = (e == f0) ? SCALE * wb0 : (e == f1) ? SCALE * wb1 : 0.0f;
    Mb[(size_t)(t >> 6) * 4096 + ((l >> 3) * 64 + (t & 63)) * 8 + (l & 7)]
        = (_Float16)(coef * mid);
}

// ---- GEMM2: out[8192x4096] = Mbig[8192x64] @ WbF[64x4096] -------------------
__global__ __launch_bounds__(256)
void g2(const _Float16* __restrict__ Mb, const _Float16* __restrict__ WbB,
        float* __restrict__ out) {
    __shared__ _Float16 lA[4096];    // 8 KB  (64-token A panel)
    __shared__ _Float16 lB[16384];   // 32 KB (256-col Wb panel)
    const int tx = threadIdx.x, l = tx & 63, w = tx >> 6;
    const int nt = blockIdx.x;       // 0..15
    const int mt = blockIdx.y;       // 0..127

    {   const uint4* g = (const uint4*)(Mb + (size_t)mt * 4096);
        uint4* d = (uint4*)lA;
        d[tx] = g[tx]; d[256 + tx] = g[256 + tx]; }
    {   const uint4* g = (const uint4*)(WbB + (size_t)nt * 16384);
        uint4* d = (uint4*)lB;
#pragma unroll
        for (int j = 0; j < 8; ++j) d[j * 256 + tx] = g[j * 256 + tx]; }
    __syncthreads();

    f4v acc[4][4];
#pragma unroll
    for (int mf = 0; mf < 4; ++mf)
#pragma unroll
        for (int nf = 0; nf < 4; ++nf) acc[mf][nf] = (f4v){0.f, 0.f, 0.f, 0.f};

#pragma unroll
    for (int ks = 0; ks < 2; ++ks) {
        h8 a[4], b[4];
#pragma unroll
        for (int mf = 0; mf < 4; ++mf)
            a[mf] = *(const h8*)(lA + ((ks * 4 + (l >> 4)) * 64 + mf * 16 + (l & 15)) * 8);
#pragma unroll
        for (int nf = 0; nf < 4; ++nf)
            b[nf] = *(const h8*)(lB + ((ks * 4 + (l >> 4)) * 256 + w * 64 + nf * 16 + (l & 15)) * 8);
#pragma unroll
        for (int mf = 0; mf < 4; ++mf)
#pragma unroll
            for (int nf = 0; nf < 4; ++nf)
                acc[mf][nf] = __builtin_amdgcn_mfma_f32_16x16x32_f16(a[mf], b[nf], acc[mf][nf], 0, 0, 0);
    }

#pragma unroll
    for (int mf = 0; mf < 4; ++mf)
#pragma unroll
        for (int nf = 0; nf < 4; ++nf)
#pragma unroll
            for (int r = 0; r < 4; ++r)
                out[(size_t)(mt * 64 + mf * 16 + (l >> 4) * 4 + r) * D_OUT
                    + nt * 256 + w * 64 + nf * 16 + (l & 15)] = acc[mf][nf][r];
}

// ---------------- aux losses: deterministic two-stage f64 reduction ----------
__global__ void aux_partial(const float* __restrict__ la, const float* __restrict__ lb,
                            double* __restrict__ part) {
    const int tx = threadIdx.x;
    const int t  = blockIdx.x * 256 + tx;
    double loc[16];
    {
        float l[8];
#pragma unroll
        for (int i = 0; i < 8; ++i) l[i] = la[t * 8 + i];
        float m = l[0];
#pragma unroll
        for (int i = 1; i < 8; ++i) m = fmaxf(m, l[i]);
        float s = 0.f; float e[8];
#pragma unroll
        for (int i = 0; i < 8; ++i) { e[i] = __expf(l[i] - m); s += e[i]; }
#pragma unroll
        for (int i = 0; i < 8; ++i) loc[i] = (double)(e[i] / s);
    }
    {
        float l[8];
#pragma unroll
        for (int i = 0; i < 8; ++i) l[i] = lb[t * 8 + i];
        float m = l[0];
#pragma unroll
        for (int i = 1; i < 8; ++i) m = fmaxf(m, l[i]);
        float s = 0.f; float e[8];
#pragma unroll
        for (int i = 0; i < 8; ++i) { e[i] = __expf(l[i] - m); s += e[i]; }
#pragma unroll
        for (int i = 0; i < 8; ++i) loc[8 + i] = (double)(e[i] / s);
    }
    __shared__ double red[4][16];
    const int lane = tx & 63, wid = tx >> 6;
#pragma unroll
    for (int v = 0; v < 16; ++v) {
        double s = loc[v];
#pragma unroll
        for (int off = 32; off > 0; off >>= 1) s += __shfl_down(s, off, 64);
        if (lane == 0) red[wid][v] = s;
    }
    __syncthreads();
    if (tx < 16)
        part[blockIdx.x * 16 + tx] = red[0][tx] + red[1][tx] + red[2][tx] + red[3][tx];
}

__global__ void aux_final(const double* __restrict__ part, float* __restrict__ out_aux) {
    const int tx = threadIdx.x;
    __shared__ double sl[16];
    if (tx < 16) {
        double s = 0.0;
#pragma unroll
        for (int b = 0; b < 32; ++b) s += part[b * 16 + tx];
        sl[tx] = s;
    }
    __syncthreads();
    if (tx == 0) {
        double pa[8], pb[8], ma = 0.0, mb = 0.0;
        for (int e = 0; e < 8; ++e) { pa[e] = sl[e] / 8192.0;     ma += pa[e] / 8.0; }
        for (int e = 0; e < 8; ++e) { pb[e] = sl[8 + e] / 8192.0; mb += pb[e] / 8.0; }
        double va = 0.0, vb = 0.0;
        for (int e = 0; e < 8; ++e) { double d = pa[e] - ma; va += d * d; }
        for (int e = 0; e < 8; ++e) { double d = pb[e] - mb; vb += d * d; }
        va /= 7.0; vb /= 7.0;
        out_aux[0] = (float)(8.0 * va);
        out_aux[1] = (float)(8.0 * vb);
    }
}

extern "C" void kernel_launch(void* const* d_in, const int* in_sizes, int n_in,
                              void* d_out, int out_size, void* d_ws, size_t ws_size,
                              hipStream_t stream) {
    const float* x  = (const float*)d_in[0];
    const float* la = (const float*)d_in[1];
    const float* lb = (const float*)d_in[2];
    const float* Wa = (const float*)d_in[3];
    const float* Wb = (const float*)d_in[4];
    float* out = (float*)d_out;

    char* ws = (char*)d_ws;
    _Float16* WaB = (_Float16*)ws;                       // 512 KB
    _Float16* WbB = (_Float16*)(ws + 524288);            // 512 KB
    _Float16* Mb  = (_Float16*)(ws + 1048576);           // 1 MB
    double*   pax = (double*)(ws + 2097152);             // 4 KB
    float*    p1  = (float*)(ws + 2162688);              // KSPLIT x 2 MB

    const size_t base = 2162688;
    int ksplit = (ws_size >= base + 4u * 2097152u) ? 4
               : (ws_size >= base + 2u * 2097152u) ? 2 : 1;
    int kch = D_IN / ksplit;

    cwa<<<256, 256, 0, stream>>>(Wa, WaB);
    cwb<<<1024, 256, 0, stream>>>(Wb, WbB);
    aux_partial<<<32, 256, 0, stream>>>(la, lb, pax);
    g1<<<dim3(256, ksplit), 256, 0, stream>>>(x, WaB, p1, kch);
    comb<<<2048, 256, 0, stream>>>(p1, la, lb, Mb, ksplit);
    g2<<<dim3(16, 128), 256, 0, stream>>>(Mb, WbB, out);
    aux_final<<<1, 64, 0, stream>>>(pax, out + (size_t)T_TOK * D_OUT);
}